// Round 11
// baseline (294.873 us; speedup 1.0000x reference)
//
#include <hip/hip_runtime.h>
#include <hip/hip_bf16.h>

#define DIM 256
#define HW  1024  // 32*32

typedef __attribute__((ext_vector_type(8))) short short8;
typedef __attribute__((ext_vector_type(4))) float floatx4;
typedef __attribute__((ext_vector_type(16))) float floatx16;

__device__ inline unsigned short f2bf(float f) {
  union { float f; unsigned u; } v;
  v.f = f;
  unsigned u = v.u;
  u += 0x7fffu + ((u >> 16) & 1u);
  return (unsigned short)(u >> 16);
}

// ---------------------------------------------------------------------------
// Dtype detector: flag=1 if inputs are fp32, 0 if bf16 (see R2 notes).
// ---------------------------------------------------------------------------
__global__ void detect_kernel(const unsigned short* __restrict__ xr,
                              int* __restrict__ flag) {
  __shared__ int cnt;
  if (threadIdx.x == 0) cnt = 0;
  __syncthreads();
  int local = 0;
  for (int i = threadIdx.x; i < 8192; i += 256) {
    unsigned short u = xr[i];
    if ((u & 0x7F80u) == 0x7F80u) local++;
  }
  if (local) atomicAdd(&cnt, local);
  __syncthreads();
  if (threadIdx.x == 0) *flag = (cnt > 0) ? 1 : 0;
}

__device__ inline float ldin(const void* p, long i, int isf32) {
  if (isf32) return ((const float*)p)[i];
  union { unsigned u; float f; } v;
  v.u = ((unsigned)((const unsigned short*)p)[i]) << 16;
  return v.f;
}

// ---------------------------------------------------------------------------
// Fused prep kernel: x->bf16, conv/wp weights -> MFMA-fragment order bf16,
// biases -> fp32.
// wF layout: [tap][c8(8)][co16(16)][lane(64)][j(8)]  where
//   co = co16*16 + (lane&15), ci = c8*32 + (lane>>4)*8 + j
// ---------------------------------------------------------------------------
__device__ inline void frag_repack(const void* __restrict__ w,
                                   unsigned short* __restrict__ wF, int KK,
                                   int local_blk, int t, int isf32) {
  const int idx = local_blk * 256 + t;
  const int j    = idx & 7;
  const int lane = (idx >> 3) & 63;
  const int co16 = (idx >> 9) & 15;
  const int c8   = (idx >> 13) & 7;
  const int tap  = idx >> 16;
  const int co = (co16 << 4) | (lane & 15);
  const int ci = (c8 << 5) + ((lane >> 4) << 3) + j;
  wF[idx] = f2bf(ldin(w, (long)(co * 256 + ci) * KK + tap, isf32));
}

__global__ void prep_kernel(const void* __restrict__ x,
                            const void* __restrict__ w3,
                            const void* __restrict__ b3,
                            const void* __restrict__ w5,
                            const void* __restrict__ b5,
                            const void* __restrict__ w7,
                            const void* __restrict__ b7,
                            const void* __restrict__ wp,
                            unsigned short* __restrict__ xbf,
                            unsigned short* __restrict__ wF3,
                            unsigned short* __restrict__ wF5,
                            unsigned short* __restrict__ wF7,
                            unsigned short* __restrict__ wpF,
                            float* __restrict__ bc,  // [3][256] q,v,k
                            const int* __restrict__ flag) {
  const int isf32 = *flag;
  const int bid = blockIdx.x;
  const int t = threadIdx.x;
  if (bid < 2048) {            // x -> bf16, 4 elem/thread
    const int i = (bid * 256 + t) * 4;
    if (isf32) {
      const float4 v = *(const float4*)((const float*)x + i);
      ushort4 o;
      o.x = f2bf(v.x); o.y = f2bf(v.y); o.z = f2bf(v.z); o.w = f2bf(v.w);
      *(ushort4*)(xbf + i) = o;
    } else {
      *(ushort4*)(xbf + i) = *(const ushort4*)((const unsigned short*)x + i);
    }
  } else if (bid < 2304) {
    frag_repack(w3, wF3, 1, bid - 2048, t, isf32);
  } else if (bid < 4608) {
    frag_repack(w5, wF5, 9, bid - 2304, t, isf32);
  } else if (bid < 11008) {
    frag_repack(w7, wF7, 25, bid - 4608, t, isf32);
  } else if (bid < 11264) {
    frag_repack(wp, wpF, 1, bid - 11008, t, isf32);
  } else {                     // biases: 768 elements (q=b3, v=b5, k=b7)
#pragma unroll
    for (int r = 0; r < 3; ++r) {
      const int i = r * 256 + t;
      const void* src = (i < 256) ? b3 : (i < 512) ? b5 : b7;
      bc[i] = ldin(src, i & 255, isf32);
    }
  }
}

// ---------------------------------------------------------------------------
// R11: FUSED q/v/k conv (R9 verified structure), geometry 128 pos x 16 co.
// Grid = 64 m-tiles x 16 co-slices = 1024 blocks = 4/CU (launch_bounds(256,4)).
// vs R9 (32-co blocks, 2/CU): per-wave B-load instructions halve (VMEM-issue
// was ~72K cyc/CU: 64-lane x 16B loads cost ~16 TA-cycles each) and waves/SIMD
// double (2->4) for latency hiding. R10's non-temporal stores reverted (they
// 8x'd WRITE_SIZE: nt scatter stores bypass L2 write-combining).
// Attention coords (R2-verified): slab=(b<<4)+(co>>4), m=(co&15)*64+(n>>4),
//   d=n&15;  q/k rows: (slab<<14)+((co&15)<<10)+n (contig in n)
//   v (V^T): (slab<<14)+((n&15)<<10)+((co&15)<<6)+(n>>4)
// ---------------------------------------------------------------------------
__global__ __launch_bounds__(256, 4) void convqkv_kernel(
    const unsigned short* __restrict__ xbf,
    const unsigned short* __restrict__ wFq,  // 1 tap
    const unsigned short* __restrict__ wFv,  // 9 taps
    const unsigned short* __restrict__ wFk,  // 25 taps
    const float* __restrict__ bc,            // [3][256] q,v,k
    unsigned short* __restrict__ qOut,
    unsigned short* __restrict__ vOut,
    unsigned short* __restrict__ kOut) {
  constexpr int WC = 36;          // halo cols (32 + 2*2)
  constexpr int LOADS = 288 * 4;  // 288 cells x 4 uint4
  __shared__ unsigned short Xs[288 * 40];  // [cell][32ci pad40]
  const int t    = threadIdx.x;
  const int bid  = blockIdx.x;
  const int cog0 = bid & 15;           // single co16 tile (16 co)
  const int co0  = cog0 << 4;
  const int m0   = (bid >> 4) << 7;    // 128 positions
  const int b    = m0 >> 10;
  const int n0   = m0 & 1023;
  const int r0   = n0 >> 5;            // first of 4 image rows
  const int wv   = t >> 6;             // wave = image row r0+wv
  const int lane = t & 63;
  const int l15  = lane & 15;
  const int quad = lane >> 4;

  floatx4 aq[2] = {}, av[2] = {}, ak[2] = {};

  for (int c8 = 0; c8 < 8; ++c8) {
    // ---- chunk-start: issue halo + q-B + tap0/1 k-B loads ----
    uint4 xreg[5];
    int idv[5];
#pragma unroll
    for (int rr = 0; rr < 5; ++rr) {
      const int id = rr * 256 + t;
      const int cell = id >> 2, part = id & 3;
      const int hr = cell / WC, wc = cell - hr * WC;
      const int xr = r0 + hr - 2, xc = wc - 2;
      const bool ok = (id < LOADS) && ((unsigned)xr < 32u) &&
                      ((unsigned)xc < 32u);
      const int cr = xr < 0 ? 0 : (xr > 31 ? 31 : xr);
      const int cc = xc < 0 ? 0 : (xc > 31 ? 31 : xc);
      uint4 v = *(const uint4*)&xbf[(((b * 32 + cr) * 32 + cc) << 8) +
                                    (c8 << 5) + (part << 3)];
      if (!ok) v = make_uint4(0, 0, 0, 0);
      xreg[rr] = v;
      idv[rr] = id;
    }
    const short8 qb =
        *(const short8*)&wFq[((c8 << 4) + cog0) * 512 + (lane << 3)];
    short8 pk[2], pv[2];
    pk[0] = *(const short8*)&wFk[((c8 << 4) + cog0) * 512 + (lane << 3)];
    pk[1] = *(const short8*)&wFk[(((1 << 7) + (c8 << 4) + cog0)) * 512 +
                                 (lane << 3)];
    __syncthreads();  // previous chunk's Xs reads done
#pragma unroll
    for (int rr = 0; rr < 5; ++rr) {
      const int id = idv[rr];
      if (id < LOADS)
        *(uint4*)&Xs[(id >> 2) * 40 + ((id & 3) << 3)] = xreg[rr];
    }
    __syncthreads();

    // ---- tap loop: 25 taps, depth-2 B prefetch, shared A fragments ----
#pragma unroll
    for (int tap = 0; tap < 25; ++tap) {
      const int s = tap & 1;
      const int kh = tap / 5, kw = tap % 5;
      const bool vv = (kh >= 1 && kh <= 3 && kw >= 1 && kw <= 3);
      // prefetch tap+2 (conditions constant-folded per unrolled iteration)
      short8 nk = {}, nv = {};
      const int nt = tap + 2;
      const bool nvalid = nt < 25;
      const int nkh = nt / 5, nkw = nt % 5;
      const bool nvv =
          nvalid && (nkh >= 1 && nkh <= 3 && nkw >= 1 && nkw <= 3);
      if (nvalid) {
        nk = *(const short8*)&wFk[((((nt << 3) + c8) << 4) + cog0) * 512 +
                                  (lane << 3)];
      }
      if (nvv) {
        const int nvt = (nkh - 1) * 3 + (nkw - 1);
        nv = *(const short8*)&wFv[((((nvt << 3) + c8) << 4) + cog0) * 512 +
                                  (lane << 3)];
      }
      // A fragments (shared by k/v/q)
      const unsigned short* xs =
          &Xs[((wv + kh) * WC + l15 + kw) * 40 + (quad << 3)];
      const short8 a0 = *(const short8*)xs;
      const short8 a1 = *(const short8*)(xs + 16 * 40);
      ak[0] = __builtin_amdgcn_mfma_f32_16x16x32_bf16(a0, pk[s], ak[0],
                                                      0, 0, 0);
      ak[1] = __builtin_amdgcn_mfma_f32_16x16x32_bf16(a1, pk[s], ak[1],
                                                      0, 0, 0);
      if (vv) {
        av[0] = __builtin_amdgcn_mfma_f32_16x16x32_bf16(a0, pv[s], av[0],
                                                        0, 0, 0);
        av[1] = __builtin_amdgcn_mfma_f32_16x16x32_bf16(a1, pv[s], av[1],
                                                        0, 0, 0);
      }
      if (tap == 12) {
        aq[0] = __builtin_amdgcn_mfma_f32_16x16x32_bf16(a0, qb, aq[0],
                                                        0, 0, 0);
        aq[1] = __builtin_amdgcn_mfma_f32_16x16x32_bf16(a1, qb, aq[1],
                                                        0, 0, 0);
      }
      pk[s] = nk;
      if (nvv) pv[s] = nv;
    }
  }
  // ---- epilogues (layout algebra identical to R5-verified code) ----
#pragma unroll
  for (int mi = 0; mi < 2; ++mi) {
    const int co = co0 + l15;
    const int slab = (b << 4) + (co >> 4);
    const int clo = co & 15;
    const int nb = n0 + (wv << 5) + (mi << 4) + (quad << 2);
    // q: QK-row layout, 4 contig n
    {
      const float bj = bc[co];
      floatx4 a = aq[mi];
      ushort4 pk4;
      pk4.x = f2bf(a[0] + bj); pk4.y = f2bf(a[1] + bj);
      pk4.z = f2bf(a[2] + bj); pk4.w = f2bf(a[3] + bj);
      *(ushort4*)&qOut[(slab << 14) + (clo << 10) + nb] = pk4;
    }
    // k: QK-row layout
    {
      const float bj = bc[512 + co];
      floatx4 a = ak[mi];
      ushort4 pk4;
      pk4.x = f2bf(a[0] + bj); pk4.y = f2bf(a[1] + bj);
      pk4.z = f2bf(a[2] + bj); pk4.w = f2bf(a[3] + bj);
      *(ushort4*)&kOut[(slab << 14) + (clo << 10) + nb] = pk4;
    }
    // v: V^T scatter
    {
      const float bj = bc[256 + co];
      floatx4 a = av[mi];
      const int base = (slab << 14) + (clo << 6);
#pragma unroll
      for (int i = 0; i < 4; ++i) {
        const int n = nb + i;
        vOut[base + ((n & 15) << 10) + (n >> 4)] = f2bf(a[i] + bj);
      }
    }
  }
}

// ---------------------------------------------------------------------------
// MFMA attention per (b,h) slab: softmax(Q K^T * 0.25) V.  [R5-verified]
//   qg, kg : bf16 [slab][1024 m][16 d];  vg : bf16 [slab][16 d][1024 m]
//   out2   : bf16 [8][1024 m][256], c = h*16+d
// ---------------------------------------------------------------------------
__global__ __launch_bounds__(256) void attn_mfma_kernel(
    const unsigned short* __restrict__ qg,
    const unsigned short* __restrict__ kg,
    const unsigned short* __restrict__ vg,
    unsigned short* __restrict__ out2) {
  __shared__ __align__(16) unsigned short Kc[16384];     // [key][16]
  __shared__ __align__(16) unsigned short Vt[16][1032];  // [d][key], padded
  __shared__ __align__(16) unsigned short Pb[4][32][40]; // per-wave P
  __shared__ float lb[4][32];
  const int t    = threadIdx.x;
  const int w    = t >> 6;
  const int lane = t & 63;
  const int slab = blockIdx.x >> 3;
  const int rb   = blockIdx.x & 7;
  const int b = slab >> 4;
  const int h = slab & 15;
  const int l31  = lane & 31;
  const int hl   = lane >> 5;
  const int l15  = lane & 15;
  const int quad = lane >> 4;

#pragma unroll
  for (int j = 0; j < 8; ++j) {
    const int id = (j << 8) + t;
    const int e  = id << 3;
    *(uint4*)&Kc[e] = *(const uint4*)&kg[(slab << 14) + e];
    const int d = e >> 10, ky = e & 1023;
    *(uint4*)&Vt[d][ky] = *(const uint4*)&vg[(slab << 14) + e];
  }

  const int row0 = (rb << 7) + (w << 5);
  const short8 qa =
      *(const short8*)&qg[(slab << 14) + ((row0 + l31) << 4) + (hl << 3)];

  float lsum[16] = {};
  floatx4 acco[2] = {};
  const float sc = 0.25f * 1.4426950408889634f;

  __syncthreads();

  for (int kc = 0; kc < 1024; kc += 32) {
    const short8 kb = *(const short8*)&Kc[((kc + l31) << 4) + (hl << 3)];
    floatx16 s = {};
    s = __builtin_amdgcn_mfma_f32_32x32x16_bf16(qa, kb, s, 0, 0, 0);
#pragma unroll
    for (int r = 0; r < 16; ++r) {
      const float e = exp2f(s[r] * sc);
      lsum[r] += e;
      const int row = (r & 3) + ((r >> 2) << 3) + (hl << 2);
      Pb[w][row][l31] = f2bf(e);
    }
    const short8 vb = *(const short8*)&Vt[l15][kc + (quad << 3)];
#pragma unroll
    for (int tt = 0; tt < 2; ++tt) {
      const short8 pa = *(const short8*)&Pb[w][(tt << 4) + l15][quad << 3];
      acco[tt] =
          __builtin_amdgcn_mfma_f32_16x16x32_bf16(pa, vb, acco[tt], 0, 0, 0);
    }
  }

#pragma unroll
  for (int r = 0; r < 16; ++r) {
    float lv = lsum[r];
    lv += __shfl_xor(lv, 1, 64);
    lv += __shfl_xor(lv, 2, 64);
    lv += __shfl_xor(lv, 4, 64);
    lv += __shfl_xor(lv, 8, 64);
    lv += __shfl_xor(lv, 16, 64);
    lsum[r] = lv;
  }
  {
    const int rr = l31;
    if (((rr >> 2) & 1) == hl) {
      const int reg = (rr & 3) + ((rr >> 3) << 2);
      lb[w][rr] = 1.0f / lsum[reg];
    }
  }
#pragma unroll
  for (int tt = 0; tt < 2; ++tt) {
#pragma unroll
    for (int r = 0; r < 4; ++r) {
      const int nloc = (tt << 4) + (quad << 2) + r;
      const float val = acco[tt][r] * lb[w][nloc];
      const int n = row0 + nloc;
      out2[(((b << 10) + n) << 8) + (h << 4) + l15] = f2bf(val);
    }
  }
}

// ---------------------------------------------------------------------------
// Final linear, MFMA bf16, with one-chunk-ahead B register prefetch.
// ---------------------------------------------------------------------------
__global__ __launch_bounds__(256) void linear_mfma_kernel(
    const unsigned short* __restrict__ inp,  // bf16 [8192][256]
    const unsigned short* __restrict__ wpF,  // fragment order
    void* __restrict__ out, const int* __restrict__ flag) {
  __shared__ unsigned short As[64 * 40];
  const int isf32 = *flag;
  const int t   = threadIdx.x;
  const int m0  = blockIdx.x << 6;
  const int co0 = blockIdx.y << 6;
  const int wv   = t >> 6;
  const int lane = t & 63;
  const int wm = (wv & 1) << 5;
  const int wn = (wv >> 1) << 5;
  const int l15  = lane & 15;
  const int quad = lane >> 4;
  const int cogb = (co0 >> 4) + (wn >> 4);
  const int rowS = t >> 2;
  const int partS = t & 3;

  floatx4 acc[2][2] = {};

  short8 cb0, cb1;
  {
    const unsigned short* wptr = &wpF[(cogb << 9) + (lane << 3)];
    cb0 = *(const short8*)wptr;
    cb1 = *(const short8*)(wptr + 512);
  }
  for (int c8 = 0; c8 < 8; ++c8) {
    const uint4 v = *(const uint4*)&inp[((m0 + rowS) << 8) + (c8 << 5) +
                                        (partS << 3)];
    short8 nb0 = {}, nb1 = {};
    if (c8 + 1 < 8) {
      const unsigned short* wptr =
          &wpF[((((c8 + 1) << 4) + cogb) << 9) + (lane << 3)];
      nb0 = *(const short8*)wptr;
      nb1 = *(const short8*)(wptr + 512);
    }
    __syncthreads();
    *(uint4*)&As[rowS * 40 + (partS << 3)] = v;
    __syncthreads();
    const unsigned short* xs = &As[(wm + l15) * 40 + (quad << 3)];
    const short8 afr0 = *(const short8*)xs;
    const short8 afr1 = *(const short8*)(xs + 16 * 40);
    acc[0][0] = __builtin_amdgcn_mfma_f32_16x16x32_bf16(afr0, cb0,
                                                        acc[0][0], 0, 0, 0);
    acc[0][1] = __builtin_amdgcn_mfma_f32_16x16x32_bf16(afr0, cb1,
                                                        acc[0][1], 0, 0, 0);
    acc[1][0] = __builtin_amdgcn_mfma_f32_16x16x32_bf16(afr1, cb0,
                                                        acc[1][0], 0, 0, 0);
    acc[1][1] = __builtin_amdgcn_mfma_f32_16x16x32_bf16(afr1, cb1,
                                                        acc[1][1], 0, 0, 0);
    cb0 = nb0; cb1 = nb1;
  }
#pragma unroll
  for (int mi = 0; mi < 2; ++mi) {
#pragma unroll
    for (int ni = 0; ni < 2; ++ni) {
      const int co = co0 + wn + (ni << 4) + l15;
      const int mb = m0 + wm + (mi << 4) + (quad << 2);
      floatx4 a = acc[mi][ni];
      if (!isf32) {
        unsigned short* o16 = (unsigned short*)out;
#pragma unroll
        for (int r = 0; r < 4; ++r) o16[(mb + r) * 256 + co] = f2bf(a[r]);
      } else {
        float* o32 = (float*)out;
#pragma unroll
        for (int r = 0; r < 4; ++r) o32[(mb + r) * 256 + co] = a[r];
      }
    }
  }
}

// ---------------------------------------------------------------------------
extern "C" void kernel_launch(void* const* d_in, const int* in_sizes, int n_in,
                              void* d_out, int out_size, void* d_ws,
                              size_t ws_size, hipStream_t stream) {
  const void* x  = d_in[0];
  const void* w3 = d_in[1];
  const void* b3 = d_in[2];
  const void* w5 = d_in[3];
  const void* b5 = d_in[4];
  const void* w7 = d_in[5];
  const void* b7 = d_in[6];
  const void* wp = d_in[7];

  char* p = (char*)d_ws;
  int* flag = (int*)p;                       p += 256;
  unsigned short* xbf = (unsigned short*)p;  p += 4u * 1024 * 1024;
  unsigned short* wF3 = (unsigned short*)p;  p += 131072;
  unsigned short* wF5 = (unsigned short*)p;  p += 1179648;
  unsigned short* wF7 = (unsigned short*)p;  p += 3276800;
  unsigned short* wpF = (unsigned short*)p;  p += 131072;
  float* bc = (float*)p;                     p += 4096;     // [3][256]
  unsigned short* qc  = (unsigned short*)p;  p += 4194304;  // bf16 QK rows
  unsigned short* kT  = (unsigned short*)p;  p += 4194304;  // bf16 QK rows
  unsigned short* vT  = (unsigned short*)p;  p += 4194304;  // bf16 V^T
  unsigned short* o2b = (unsigned short*)p;  p += 4194304;  // bf16 [8192][256]

  detect_kernel<<<1, 256, 0, stream>>>((const unsigned short*)x, flag);

  prep_kernel<<<11265, 256, 0, stream>>>(x, w3, b3, w5, b5, w7, b7, wp, xbf,
                                         wF3, wF5, wF7, wpF, bc, flag);

  convqkv_kernel<<<1024, 256, 0, stream>>>(xbf, wF3, wF5, wF7, bc, qc, vT, kT);

  attn_mfma_kernel<<<1024, 256, 0, stream>>>(qc, kT, vT, o2b);

  dim3 lg(128, 4);
  linear_mfma_kernel<<<lg, 256, 0, stream>>>(o2b, wpF, d_out, flag);
}

// Round 12
// 273.023 us; speedup vs baseline: 1.0800x; 1.0800x over previous
//
#include <hip/hip_runtime.h>
#include <hip/hip_bf16.h>

#define DIM 256
#define HW  1024  // 32*32

typedef __attribute__((ext_vector_type(8))) short short8;
typedef __attribute__((ext_vector_type(4))) float floatx4;
typedef __attribute__((ext_vector_type(16))) float floatx16;

__device__ inline unsigned short f2bf(float f) {
  union { float f; unsigned u; } v;
  v.f = f;
  unsigned u = v.u;
  u += 0x7fffu + ((u >> 16) & 1u);
  return (unsigned short)(u >> 16);
}

// ---------------------------------------------------------------------------
// Dtype detector: flag=1 if inputs are fp32, 0 if bf16 (see R2 notes).
// ---------------------------------------------------------------------------
__global__ void detect_kernel(const unsigned short* __restrict__ xr,
                              int* __restrict__ flag) {
  __shared__ int cnt;
  if (threadIdx.x == 0) cnt = 0;
  __syncthreads();
  int local = 0;
  for (int i = threadIdx.x; i < 8192; i += 256) {
    unsigned short u = xr[i];
    if ((u & 0x7F80u) == 0x7F80u) local++;
  }
  if (local) atomicAdd(&cnt, local);
  __syncthreads();
  if (threadIdx.x == 0) *flag = (cnt > 0) ? 1 : 0;
}

__device__ inline float ldin(const void* p, long i, int isf32) {
  if (isf32) return ((const float*)p)[i];
  union { unsigned u; float f; } v;
  v.u = ((unsigned)((const unsigned short*)p)[i]) << 16;
  return v.f;
}

// ---------------------------------------------------------------------------
// Fused prep kernel: x->bf16, conv/wp weights -> MFMA-fragment order bf16,
// biases -> fp32.
// wF layout: [tap][c8(8)][co16(16)][lane(64)][j(8)]  where
//   co = co16*16 + (lane&15), ci = c8*32 + (lane>>4)*8 + j
// ---------------------------------------------------------------------------
__device__ inline void frag_repack(const void* __restrict__ w,
                                   unsigned short* __restrict__ wF, int KK,
                                   int local_blk, int t, int isf32) {
  const int idx = local_blk * 256 + t;
  const int j    = idx & 7;
  const int lane = (idx >> 3) & 63;
  const int co16 = (idx >> 9) & 15;
  const int c8   = (idx >> 13) & 7;
  const int tap  = idx >> 16;
  const int co = (co16 << 4) | (lane & 15);
  const int ci = (c8 << 5) + ((lane >> 4) << 3) + j;
  wF[idx] = f2bf(ldin(w, (long)(co * 256 + ci) * KK + tap, isf32));
}

__global__ void prep_kernel(const void* __restrict__ x,
                            const void* __restrict__ w3,
                            const void* __restrict__ b3,
                            const void* __restrict__ w5,
                            const void* __restrict__ b5,
                            const void* __restrict__ w7,
                            const void* __restrict__ b7,
                            const void* __restrict__ wp,
                            unsigned short* __restrict__ xbf,
                            unsigned short* __restrict__ wF3,
                            unsigned short* __restrict__ wF5,
                            unsigned short* __restrict__ wF7,
                            unsigned short* __restrict__ wpF,
                            float* __restrict__ bc,  // [3][256] q,v,k
                            const int* __restrict__ flag) {
  const int isf32 = *flag;
  const int bid = blockIdx.x;
  const int t = threadIdx.x;
  if (bid < 2048) {            // x -> bf16, 4 elem/thread
    const int i = (bid * 256 + t) * 4;
    if (isf32) {
      const float4 v = *(const float4*)((const float*)x + i);
      ushort4 o;
      o.x = f2bf(v.x); o.y = f2bf(v.y); o.z = f2bf(v.z); o.w = f2bf(v.w);
      *(ushort4*)(xbf + i) = o;
    } else {
      *(ushort4*)(xbf + i) = *(const ushort4*)((const unsigned short*)x + i);
    }
  } else if (bid < 2304) {
    frag_repack(w3, wF3, 1, bid - 2048, t, isf32);
  } else if (bid < 4608) {
    frag_repack(w5, wF5, 9, bid - 2304, t, isf32);
  } else if (bid < 11008) {
    frag_repack(w7, wF7, 25, bid - 4608, t, isf32);
  } else if (bid < 11264) {
    frag_repack(wp, wpF, 1, bid - 11008, t, isf32);
  } else {                     // biases: 768 elements (q=b3, v=b5, k=b7)
#pragma unroll
    for (int r = 0; r < 3; ++r) {
      const int i = r * 256 + t;
      const void* src = (i < 256) ? b3 : (i < 512) ? b5 : b7;
      bc[i] = ldin(src, i & 255, isf32);
    }
  }
}

// ---------------------------------------------------------------------------
// R12: FUSED q/v/k conv. Tap loop is now 100% LDS-fed: per 32-ci chunk we
// bulk-stage the x-halo (23 KB) AND all 35 taps' B-fragments (36 KB) into
// LDS in one shot (14 dwordx4/thread, single drain, one barrier pair), then
// run 25 taps of pure ds_read+MFMA with no global loads and no barriers.
// This removes the per-tap global B loads that were the invariant of the
// R6-R11 70-142us plateau (4 waves/block re-loading identical 70KB/chunk
// through L2 with only 2 waves/SIMD of latency cover).
// Geometry: Tm=128 (4 rows, 1/wave) x Tco=16; grid 64x16=1024, 2 blocks/CU
// (512 resident = the L2-safe residency; R11's 4/CU thrashed per-XCD L2:
// FETCH 168MB). LDS 58.5 KB static.
// Attention coords (R2/R11-verified): slab=(b<<4)+(co>>4), m=(co&15)*64+(n>>4),
//   d=n&15;  q/k rows: (slab<<14)+((co&15)<<10)+n ;  v (V^T):
//   (slab<<14)+((n&15)<<10)+((co&15)<<6)+(n>>4)
// ---------------------------------------------------------------------------
__global__ __launch_bounds__(256, 2) void convqkv_kernel(
    const unsigned short* __restrict__ xbf,
    const unsigned short* __restrict__ wFq,  // 1 tap
    const unsigned short* __restrict__ wFv,  // 9 taps
    const unsigned short* __restrict__ wFk,  // 25 taps
    const float* __restrict__ bc,            // [3][256] q,v,k
    unsigned short* __restrict__ qOut,
    unsigned short* __restrict__ vOut,
    unsigned short* __restrict__ kOut) {
  constexpr int WC = 36;          // halo cols (32 + 2*2)
  constexpr int LOADS = 288 * 4;  // 1152 halo dwordx4 loads (288 cells)
  __shared__ unsigned short Xs[288 * 40];  // halo [cell][32ci pad40]  23 KB
  __shared__ unsigned short Bs[36 * 512];  // B [tap35+1][lane64][8]   36 KB
  const int t    = threadIdx.x;
  const int bid  = blockIdx.x;
  const int cog0 = bid & 15;           // single co16 tile (16 co)
  const int co0  = cog0 << 4;
  const int m0   = (bid >> 4) << 7;    // 128 positions
  const int b    = m0 >> 10;
  const int n0   = m0 & 1023;
  const int r0   = n0 >> 5;            // first of 4 image rows
  const int wv   = t >> 6;             // wave = image row r0+wv
  const int lane = t & 63;
  const int l15  = lane & 15;
  const int quad = lane >> 4;

  floatx4 aq[2] = {}, av[2] = {}, ak[2] = {};

  for (int c8 = 0; c8 < 8; ++c8) {
    // ---- issue ALL staging loads for this chunk (halo + 35 taps of B) ----
    uint4 xreg[5];
    int idv[5];
#pragma unroll
    for (int rr = 0; rr < 5; ++rr) {
      const int id = rr * 256 + t;
      const int cell = id >> 2, part = id & 3;
      const int hr = cell / WC, wc = cell - hr * WC;
      const int xr = r0 + hr - 2, xc = wc - 2;
      const bool ok = (id < LOADS) && ((unsigned)xr < 32u) &&
                      ((unsigned)xc < 32u);
      const int cr = xr < 0 ? 0 : (xr > 31 ? 31 : xr);
      const int cc = xc < 0 ? 0 : (xc > 31 ? 31 : xc);
      uint4 v = *(const uint4*)&xbf[(((b * 32 + cr) * 32 + cc) << 8) +
                                    (c8 << 5) + (part << 3)];
      if (!ok) v = make_uint4(0, 0, 0, 0);
      xreg[rr] = v;
      idv[rr] = id;
    }
    // B: 35 taps x 64 lanes x 16B. id>>6 = tap (wave-uniform: rr*4+wv).
    uint4 breg[9];
#pragma unroll
    for (int rr = 0; rr < 9; ++rr) {
      const int id  = rr * 256 + t;    // 0..2303
      const int tap = id >> 6;         // rr*4 + wv  (wave-uniform)
      const int ln  = id & 63;
      const int tapc = (tap < 35) ? tap : 34;
      const unsigned short* src;
      if (tapc < 25) {
        src = &wFk[((((tapc << 3) + c8) << 4) + cog0) * 512 + (ln << 3)];
      } else if (tapc < 34) {
        src = &wFv[(((((tapc - 25) << 3) + c8) << 4) + cog0) * 512 +
                   (ln << 3)];
      } else {
        src = &wFq[((c8 << 4) + cog0) * 512 + (ln << 3)];
      }
      breg[rr] = *(const uint4*)src;
    }
    __syncthreads();  // previous chunk's LDS reads done
#pragma unroll
    for (int rr = 0; rr < 5; ++rr) {
      const int id = idv[rr];
      if (id < LOADS)
        *(uint4*)&Xs[(id >> 2) * 40 + ((id & 3) << 3)] = xreg[rr];
    }
#pragma unroll
    for (int rr = 0; rr < 9; ++rr) {
      const int id = rr * 256 + t;
      if (id < 35 * 64)
        *(uint4*)&Bs[(id >> 6) * 512 + ((id & 63) << 3)] = breg[rr];
    }
    __syncthreads();  // halo + all B ready

    // ---- tap loop: pure LDS + MFMA, no global, no barriers ----
#pragma unroll
    for (int tap = 0; tap < 25; ++tap) {
      const int kh = tap / 5, kw = tap % 5;
      const bool vv = (kh >= 1 && kh <= 3 && kw >= 1 && kw <= 3);
      const unsigned short* xs =
          &Xs[((wv + kh) * WC + l15 + kw) * 40 + (quad << 3)];
      const short8 a0 = *(const short8*)xs;
      const short8 a1 = *(const short8*)(xs + 16 * 40);
      const short8 kb = *(const short8*)&Bs[tap * 512 + (lane << 3)];
      ak[0] = __builtin_amdgcn_mfma_f32_16x16x32_bf16(a0, kb, ak[0], 0, 0, 0);
      ak[1] = __builtin_amdgcn_mfma_f32_16x16x32_bf16(a1, kb, ak[1], 0, 0, 0);
      if (vv) {
        const int vt = (kh - 1) * 3 + (kw - 1);
        const short8 vb =
            *(const short8*)&Bs[(25 + vt) * 512 + (lane << 3)];
        av[0] = __builtin_amdgcn_mfma_f32_16x16x32_bf16(a0, vb, av[0],
                                                        0, 0, 0);
        av[1] = __builtin_amdgcn_mfma_f32_16x16x32_bf16(a1, vb, av[1],
                                                        0, 0, 0);
      }
      if (tap == 12) {
        const short8 qb = *(const short8*)&Bs[34 * 512 + (lane << 3)];
        aq[0] = __builtin_amdgcn_mfma_f32_16x16x32_bf16(a0, qb, aq[0],
                                                        0, 0, 0);
        aq[1] = __builtin_amdgcn_mfma_f32_16x16x32_bf16(a1, qb, aq[1],
                                                        0, 0, 0);
      }
    }
  }
  // ---- epilogues (byte-identical algebra to R11's PASSED kernel) ----
#pragma unroll
  for (int mi = 0; mi < 2; ++mi) {
    const int co = co0 + l15;
    const int slab = (b << 4) + (co >> 4);
    const int clo = co & 15;
    const int nb = n0 + (wv << 5) + (mi << 4) + (quad << 2);
    // q: QK-row layout, 4 contig n
    {
      const float bj = bc[co];
      floatx4 a = aq[mi];
      ushort4 pk4;
      pk4.x = f2bf(a[0] + bj); pk4.y = f2bf(a[1] + bj);
      pk4.z = f2bf(a[2] + bj); pk4.w = f2bf(a[3] + bj);
      *(ushort4*)&qOut[(slab << 14) + (clo << 10) + nb] = pk4;
    }
    // k: QK-row layout
    {
      const float bj = bc[512 + co];
      floatx4 a = ak[mi];
      ushort4 pk4;
      pk4.x = f2bf(a[0] + bj); pk4.y = f2bf(a[1] + bj);
      pk4.z = f2bf(a[2] + bj); pk4.w = f2bf(a[3] + bj);
      *(ushort4*)&kOut[(slab << 14) + (clo << 10) + nb] = pk4;
    }
    // v: V^T scatter
    {
      const float bj = bc[256 + co];
      floatx4 a = av[mi];
      const int base = (slab << 14) + (clo << 6);
#pragma unroll
      for (int i = 0; i < 4; ++i) {
        const int n = nb + i;
        vOut[base + ((n & 15) << 10) + (n >> 4)] = f2bf(a[i] + bj);
      }
    }
  }
}

// ---------------------------------------------------------------------------
// MFMA attention per (b,h) slab: softmax(Q K^T * 0.25) V.  [R5-verified]
//   qg, kg : bf16 [slab][1024 m][16 d];  vg : bf16 [slab][16 d][1024 m]
//   out2   : bf16 [8][1024 m][256], c = h*16+d
// ---------------------------------------------------------------------------
__global__ __launch_bounds__(256) void attn_mfma_kernel(
    const unsigned short* __restrict__ qg,
    const unsigned short* __restrict__ kg,
    const unsigned short* __restrict__ vg,
    unsigned short* __restrict__ out2) {
  __shared__ __align__(16) unsigned short Kc[16384];     // [key][16]
  __shared__ __align__(16) unsigned short Vt[16][1032];  // [d][key], padded
  __shared__ __align__(16) unsigned short Pb[4][32][40]; // per-wave P
  __shared__ float lb[4][32];
  const int t    = threadIdx.x;
  const int w    = t >> 6;
  const int lane = t & 63;
  const int slab = blockIdx.x >> 3;
  const int rb   = blockIdx.x & 7;
  const int b = slab >> 4;
  const int h = slab & 15;
  const int l31  = lane & 31;
  const int hl   = lane >> 5;
  const int l15  = lane & 15;
  const int quad = lane >> 4;

#pragma unroll
  for (int j = 0; j < 8; ++j) {
    const int id = (j << 8) + t;
    const int e  = id << 3;
    *(uint4*)&Kc[e] = *(const uint4*)&kg[(slab << 14) + e];
    const int d = e >> 10, ky = e & 1023;
    *(uint4*)&Vt[d][ky] = *(const uint4*)&vg[(slab << 14) + e];
  }

  const int row0 = (rb << 7) + (w << 5);
  const short8 qa =
      *(const short8*)&qg[(slab << 14) + ((row0 + l31) << 4) + (hl << 3)];

  float lsum[16] = {};
  floatx4 acco[2] = {};
  const float sc = 0.25f * 1.4426950408889634f;

  __syncthreads();

  for (int kc = 0; kc < 1024; kc += 32) {
    const short8 kb = *(const short8*)&Kc[((kc + l31) << 4) + (hl << 3)];
    floatx16 s = {};
    s = __builtin_amdgcn_mfma_f32_32x32x16_bf16(qa, kb, s, 0, 0, 0);
#pragma unroll
    for (int r = 0; r < 16; ++r) {
      const float e = exp2f(s[r] * sc);
      lsum[r] += e;
      const int row = (r & 3) + ((r >> 2) << 3) + (hl << 2);
      Pb[w][row][l31] = f2bf(e);
    }
    const short8 vb = *(const short8*)&Vt[l15][kc + (quad << 3)];
#pragma unroll
    for (int tt = 0; tt < 2; ++tt) {
      const short8 pa = *(const short8*)&Pb[w][(tt << 4) + l15][quad << 3];
      acco[tt] =
          __builtin_amdgcn_mfma_f32_16x16x32_bf16(pa, vb, acco[tt], 0, 0, 0);
    }
  }

#pragma unroll
  for (int r = 0; r < 16; ++r) {
    float lv = lsum[r];
    lv += __shfl_xor(lv, 1, 64);
    lv += __shfl_xor(lv, 2, 64);
    lv += __shfl_xor(lv, 4, 64);
    lv += __shfl_xor(lv, 8, 64);
    lv += __shfl_xor(lv, 16, 64);
    lsum[r] = lv;
  }
  {
    const int rr = l31;
    if (((rr >> 2) & 1) == hl) {
      const int reg = (rr & 3) + ((rr >> 3) << 2);
      lb[w][rr] = 1.0f / lsum[reg];
    }
  }
#pragma unroll
  for (int tt = 0; tt < 2; ++tt) {
#pragma unroll
    for (int r = 0; r < 4; ++r) {
      const int nloc = (tt << 4) + (quad << 2) + r;
      const float val = acco[tt][r] * lb[w][nloc];
      const int n = row0 + nloc;
      out2[(((b << 10) + n) << 8) + (h << 4) + l15] = f2bf(val);
    }
  }
}

// ---------------------------------------------------------------------------
// Final linear, MFMA bf16, with one-chunk-ahead B register prefetch.
// ---------------------------------------------------------------------------
__global__ __launch_bounds__(256) void linear_mfma_kernel(
    const unsigned short* __restrict__ inp,  // bf16 [8192][256]
    const unsigned short* __restrict__ wpF,  // fragment order
    void* __restrict__ out, const int* __restrict__ flag) {
  __shared__ unsigned short As[64 * 40];
  const int isf32 = *flag;
  const int t   = threadIdx.x;
  const int m0  = blockIdx.x << 6;
  const int co0 = blockIdx.y << 6;
  const int wv   = t >> 6;
  const int lane = t & 63;
  const int wm = (wv & 1) << 5;
  const int wn = (wv >> 1) << 5;
  const int l15  = lane & 15;
  const int quad = lane >> 4;
  const int cogb = (co0 >> 4) + (wn >> 4);
  const int rowS = t >> 2;
  const int partS = t & 3;

  floatx4 acc[2][2] = {};

  short8 cb0, cb1;
  {
    const unsigned short* wptr = &wpF[(cogb << 9) + (lane << 3)];
    cb0 = *(const short8*)wptr;
    cb1 = *(const short8*)(wptr + 512);
  }
  for (int c8 = 0; c8 < 8; ++c8) {
    const uint4 v = *(const uint4*)&inp[((m0 + rowS) << 8) + (c8 << 5) +
                                        (partS << 3)];
    short8 nb0 = {}, nb1 = {};
    if (c8 + 1 < 8) {
      const unsigned short* wptr =
          &wpF[((((c8 + 1) << 4) + cogb) << 9) + (lane << 3)];
      nb0 = *(const short8*)wptr;
      nb1 = *(const short8*)(wptr + 512);
    }
    __syncthreads();
    *(uint4*)&As[rowS * 40 + (partS << 3)] = v;
    __syncthreads();
    const unsigned short* xs = &As[(wm + l15) * 40 + (quad << 3)];
    const short8 afr0 = *(const short8*)xs;
    const short8 afr1 = *(const short8*)(xs + 16 * 40);
    acc[0][0] = __builtin_amdgcn_mfma_f32_16x16x32_bf16(afr0, cb0,
                                                        acc[0][0], 0, 0, 0);
    acc[0][1] = __builtin_amdgcn_mfma_f32_16x16x32_bf16(afr0, cb1,
                                                        acc[0][1], 0, 0, 0);
    acc[1][0] = __builtin_amdgcn_mfma_f32_16x16x32_bf16(afr1, cb0,
                                                        acc[1][0], 0, 0, 0);
    acc[1][1] = __builtin_amdgcn_mfma_f32_16x16x32_bf16(afr1, cb1,
                                                        acc[1][1], 0, 0, 0);
    cb0 = nb0; cb1 = nb1;
  }
#pragma unroll
  for (int mi = 0; mi < 2; ++mi) {
#pragma unroll
    for (int ni = 0; ni < 2; ++ni) {
      const int co = co0 + wn + (ni << 4) + l15;
      const int mb = m0 + wm + (mi << 4) + (quad << 2);
      floatx4 a = acc[mi][ni];
      if (!isf32) {
        unsigned short* o16 = (unsigned short*)out;
#pragma unroll
        for (int r = 0; r < 4; ++r) o16[(mb + r) * 256 + co] = f2bf(a[r]);
      } else {
        float* o32 = (float*)out;
#pragma unroll
        for (int r = 0; r < 4; ++r) o32[(mb + r) * 256 + co] = a[r];
      }
    }
  }
}

// ---------------------------------------------------------------------------
extern "C" void kernel_launch(void* const* d_in, const int* in_sizes, int n_in,
                              void* d_out, int out_size, void* d_ws,
                              size_t ws_size, hipStream_t stream) {
  const void* x  = d_in[0];
  const void* w3 = d_in[1];
  const void* b3 = d_in[2];
  const void* w5 = d_in[3];
  const void* b5 = d_in[4];
  const void* w7 = d_in[5];
  const void* b7 = d_in[6];
  const void* wp = d_in[7];

  char* p = (char*)d_ws;
  int* flag = (int*)p;                       p += 256;
  unsigned short* xbf = (unsigned short*)p;  p += 4u * 1024 * 1024;
  unsigned short* wF3 = (unsigned short*)p;  p += 131072;
  unsigned short* wF5 = (unsigned short*)p;  p += 1179648;
  unsigned short* wF7 = (unsigned short*)p;  p += 3276800;
  unsigned short* wpF = (unsigned short*)p;  p += 131072;
  float* bc = (float*)p;                     p += 4096;     // [3][256]
  unsigned short* qc  = (unsigned short*)p;  p += 4194304;  // bf16 QK rows
  unsigned short* kT  = (unsigned short*)p;  p += 4194304;  // bf16 QK rows
  unsigned short* vT  = (unsigned short*)p;  p += 4194304;  // bf16 V^T
  unsigned short* o2b = (unsigned short*)p;  p += 4194304;  // bf16 [8192][256]

  detect_kernel<<<1, 256, 0, stream>>>((const unsigned short*)x, flag);

  prep_kernel<<<11265, 256, 0, stream>>>(x, w3, b3, w5, b5, w7, b7, wp, xbf,
                                         wF3, wF5, wF7, wpF, bc, flag);

  convqkv_kernel<<<1024, 256, 0, stream>>>(xbf, wF3, wF5, wF7, bc, qc, vT, kT);

  attn_mfma_kernel<<<1024, 256, 0, stream>>>(qc, kT, vT, o2b);

  dim3 lg(128, 4);
  linear_mfma_kernel<<<lg, 256, 0, stream>>>(o2b, wpF, d_out, flag);
}

// Round 13
// 214.112 us; speedup vs baseline: 1.3772x; 1.2751x over previous
//
#include <hip/hip_runtime.h>
#include <hip/hip_bf16.h>

#define DIM 256
#define HW  1024  // 32*32

typedef __attribute__((ext_vector_type(8))) short short8;
typedef __attribute__((ext_vector_type(4))) float floatx4;
typedef __attribute__((ext_vector_type(16))) float floatx16;
typedef __attribute__((address_space(1))) const unsigned int g_u32;
typedef __attribute__((address_space(3))) unsigned int l_u32;

__device__ inline unsigned short f2bf(float f) {
  union { float f; unsigned u; } v;
  v.f = f;
  unsigned u = v.u;
  u += 0x7fffu + ((u >> 16) & 1u);
  return (unsigned short)(u >> 16);
}

// ---------------------------------------------------------------------------
// Dtype detector: flag=1 if inputs are fp32, 0 if bf16 (see R2 notes).
// ---------------------------------------------------------------------------
__global__ void detect_kernel(const unsigned short* __restrict__ xr,
                              int* __restrict__ flag) {
  __shared__ int cnt;
  if (threadIdx.x == 0) cnt = 0;
  __syncthreads();
  int local = 0;
  for (int i = threadIdx.x; i < 8192; i += 256) {
    unsigned short u = xr[i];
    if ((u & 0x7F80u) == 0x7F80u) local++;
  }
  if (local) atomicAdd(&cnt, local);
  __syncthreads();
  if (threadIdx.x == 0) *flag = (cnt > 0) ? 1 : 0;
}

__device__ inline float ldin(const void* p, long i, int isf32) {
  if (isf32) return ((const float*)p)[i];
  union { unsigned u; float f; } v;
  v.u = ((unsigned)((const unsigned short*)p)[i]) << 16;
  return v.f;
}

// ---------------------------------------------------------------------------
// Fused prep kernel: x->bf16, conv/wp weights -> MFMA-fragment order bf16,
// biases -> fp32.
// wF layout: [tap][c8(8)][co16(16)][lane(64)][j(8)]  where
//   co = co16*16 + (lane&15), ci = c8*32 + (lane>>4)*8 + j
// ---------------------------------------------------------------------------
__device__ inline void frag_repack(const void* __restrict__ w,
                                   unsigned short* __restrict__ wF, int KK,
                                   int local_blk, int t, int isf32) {
  const int idx = local_blk * 256 + t;
  const int j    = idx & 7;
  const int lane = (idx >> 3) & 63;
  const int co16 = (idx >> 9) & 15;
  const int c8   = (idx >> 13) & 7;
  const int tap  = idx >> 16;
  const int co = (co16 << 4) | (lane & 15);
  const int ci = (c8 << 5) + ((lane >> 4) << 3) + j;
  wF[idx] = f2bf(ldin(w, (long)(co * 256 + ci) * KK + tap, isf32));
}

__global__ void prep_kernel(const void* __restrict__ x,
                            const void* __restrict__ w3,
                            const void* __restrict__ b3,
                            const void* __restrict__ w5,
                            const void* __restrict__ b5,
                            const void* __restrict__ w7,
                            const void* __restrict__ b7,
                            const void* __restrict__ wp,
                            unsigned short* __restrict__ xbf,
                            unsigned short* __restrict__ wF3,
                            unsigned short* __restrict__ wF5,
                            unsigned short* __restrict__ wF7,
                            unsigned short* __restrict__ wpF,
                            float* __restrict__ bc,  // [3][256] q,v,k
                            const int* __restrict__ flag) {
  const int isf32 = *flag;
  const int bid = blockIdx.x;
  const int t = threadIdx.x;
  if (bid < 2048) {            // x -> bf16, 4 elem/thread
    const int i = (bid * 256 + t) * 4;
    if (isf32) {
      const float4 v = *(const float4*)((const float*)x + i);
      ushort4 o;
      o.x = f2bf(v.x); o.y = f2bf(v.y); o.z = f2bf(v.z); o.w = f2bf(v.w);
      *(ushort4*)(xbf + i) = o;
    } else {
      *(ushort4*)(xbf + i) = *(const ushort4*)((const unsigned short*)x + i);
    }
  } else if (bid < 2304) {
    frag_repack(w3, wF3, 1, bid - 2048, t, isf32);
  } else if (bid < 4608) {
    frag_repack(w5, wF5, 9, bid - 2304, t, isf32);
  } else if (bid < 11008) {
    frag_repack(w7, wF7, 25, bid - 4608, t, isf32);
  } else if (bid < 11264) {
    frag_repack(wp, wpF, 1, bid - 11008, t, isf32);
  } else {                     // biases: 768 elements (q=b3, v=b5, k=b7)
#pragma unroll
    for (int r = 0; r < 3; ++r) {
      const int i = r * 256 + t;
      const void* src = (i < 256) ? b3 : (i < 512) ? b5 : b7;
      bc[i] = ldin(src, i & 255, isf32);
    }
  }
}

// ---------------------------------------------------------------------------
// R13: FUSED q/v/k conv. Same LDS-fed tap loop as R12 (verified numerics),
// but B staging now uses __builtin_amdgcn_global_load_lds(16B): direct
// global->LDS DMA, zero VGPRs. R12's register-array staging (14 uint4 across
// a barrier) was demoted to scratch: 281 MB of HBM scratch writes = the 129us.
// Bs layout [tap][lane][8] is exactly the glds contract: wave-uniform base
// (tap = rr*4+wv) + lane*16B, contiguous source. Halo keeps the R9/R11-proven
// 5-uint4 register staging (pad-40 layout incompatible with glds, m104).
// Geometry: Tm=128 x Tco=16; grid 1024, 2 blocks/CU (LDS 58.5 KB).
// Attention coords (R2/R11-verified): slab=(b<<4)+(co>>4), m=(co&15)*64+(n>>4),
//   d=n&15;  q/k rows: (slab<<14)+((co&15)<<10)+n ;  v (V^T):
//   (slab<<14)+((n&15)<<10)+((co&15)<<6)+(n>>4)
// ---------------------------------------------------------------------------
__global__ __launch_bounds__(256, 2) void convqkv_kernel(
    const unsigned short* __restrict__ xbf,
    const unsigned short* __restrict__ wFq,  // 1 tap
    const unsigned short* __restrict__ wFv,  // 9 taps
    const unsigned short* __restrict__ wFk,  // 25 taps
    const float* __restrict__ bc,            // [3][256] q,v,k
    unsigned short* __restrict__ qOut,
    unsigned short* __restrict__ vOut,
    unsigned short* __restrict__ kOut) {
  constexpr int WC = 36;          // halo cols (32 + 2*2)
  constexpr int LOADS = 288 * 4;  // 1152 halo dwordx4 loads (288 cells)
  __shared__ unsigned short Xs[288 * 40];  // halo [cell][32ci pad40]  23 KB
  __shared__ unsigned short Bs[36 * 512];  // B [tap35+1][lane64][8]   36 KB
  const int t    = threadIdx.x;
  const int bid  = blockIdx.x;
  const int cog0 = bid & 15;           // single co16 tile (16 co)
  const int co0  = cog0 << 4;
  const int m0   = (bid >> 4) << 7;    // 128 positions
  const int b    = m0 >> 10;
  const int n0   = m0 & 1023;
  const int r0   = n0 >> 5;            // first of 4 image rows
  const int wv   = t >> 6;             // wave = image row r0+wv
  const int lane = t & 63;
  const int l15  = lane & 15;
  const int quad = lane >> 4;

  floatx4 aq[2] = {}, av[2] = {}, ak[2] = {};

  for (int c8 = 0; c8 < 8; ++c8) {
    // ---- halo loads into registers (R9/R11-proven, 20 VGPRs) ----
    uint4 xreg[5];
    int idv[5];
#pragma unroll
    for (int rr = 0; rr < 5; ++rr) {
      const int id = rr * 256 + t;
      const int cell = id >> 2, part = id & 3;
      const int hr = cell / WC, wc = cell - hr * WC;
      const int xr = r0 + hr - 2, xc = wc - 2;
      const bool ok = (id < LOADS) && ((unsigned)xr < 32u) &&
                      ((unsigned)xc < 32u);
      const int cr = xr < 0 ? 0 : (xr > 31 ? 31 : xr);
      const int cc = xc < 0 ? 0 : (xc > 31 ? 31 : xc);
      uint4 v = *(const uint4*)&xbf[(((b * 32 + cr) * 32 + cc) << 8) +
                                    (c8 << 5) + (part << 3)];
      if (!ok) v = make_uint4(0, 0, 0, 0);
      xreg[rr] = v;
      idv[rr] = id;
    }
    __syncthreads();  // ALL waves done reading previous chunk's Xs/Bs
    // ---- B: 35 taps via global_load_lds (no VGPR round-trip) ----
    // tap = rr*4 + wv is wave-uniform; dest = Bs + tap*1024B + lane*16B.
#pragma unroll
    for (int rr = 0; rr < 9; ++rr) {
      const int tap = (rr << 2) + wv;
      if (tap < 35) {
        const unsigned short* src;
        if (tap < 25) {
          src = &wFk[((((tap << 3) + c8) << 4) + cog0) * 512];
        } else if (tap < 34) {
          src = &wFv[(((((tap - 25) << 3) + c8) << 4) + cog0) * 512];
        } else {
          src = &wFq[((c8 << 4) + cog0) * 512];
        }
        __builtin_amdgcn_global_load_lds((g_u32*)(src + (lane << 3)),
                                         (l_u32*)&Bs[tap << 9], 16, 0, 0);
      }
    }
    // ---- halo regs -> LDS ----
#pragma unroll
    for (int rr = 0; rr < 5; ++rr) {
      const int id = idv[rr];
      if (id < LOADS)
        *(uint4*)&Xs[(id >> 2) * 40 + ((id & 3) << 3)] = xreg[rr];
    }
    __syncthreads();  // drains vmcnt (glds) + lgkm (ds_writes): all ready

    // ---- tap loop: pure LDS + MFMA, no global, no barriers (R12-verified) --
#pragma unroll
    for (int tap = 0; tap < 25; ++tap) {
      const int kh = tap / 5, kw = tap % 5;
      const bool vv = (kh >= 1 && kh <= 3 && kw >= 1 && kw <= 3);
      const unsigned short* xs =
          &Xs[((wv + kh) * WC + l15 + kw) * 40 + (quad << 3)];
      const short8 a0 = *(const short8*)xs;
      const short8 a1 = *(const short8*)(xs + 16 * 40);
      const short8 kb = *(const short8*)&Bs[(tap << 9) + (lane << 3)];
      ak[0] = __builtin_amdgcn_mfma_f32_16x16x32_bf16(a0, kb, ak[0], 0, 0, 0);
      ak[1] = __builtin_amdgcn_mfma_f32_16x16x32_bf16(a1, kb, ak[1], 0, 0, 0);
      if (vv) {
        const int vt = (kh - 1) * 3 + (kw - 1);
        const short8 vb =
            *(const short8*)&Bs[((25 + vt) << 9) + (lane << 3)];
        av[0] = __builtin_amdgcn_mfma_f32_16x16x32_bf16(a0, vb, av[0],
                                                        0, 0, 0);
        av[1] = __builtin_amdgcn_mfma_f32_16x16x32_bf16(a1, vb, av[1],
                                                        0, 0, 0);
      }
      if (tap == 12) {
        const short8 qb = *(const short8*)&Bs[(34 << 9) + (lane << 3)];
        aq[0] = __builtin_amdgcn_mfma_f32_16x16x32_bf16(a0, qb, aq[0],
                                                        0, 0, 0);
        aq[1] = __builtin_amdgcn_mfma_f32_16x16x32_bf16(a1, qb, aq[1],
                                                        0, 0, 0);
      }
    }
  }
  // ---- epilogues (byte-identical algebra to R11/R12's PASSED kernels) ----
#pragma unroll
  for (int mi = 0; mi < 2; ++mi) {
    const int co = co0 + l15;
    const int slab = (b << 4) + (co >> 4);
    const int clo = co & 15;
    const int nb = n0 + (wv << 5) + (mi << 4) + (quad << 2);
    // q: QK-row layout, 4 contig n
    {
      const float bj = bc[co];
      floatx4 a = aq[mi];
      ushort4 pk4;
      pk4.x = f2bf(a[0] + bj); pk4.y = f2bf(a[1] + bj);
      pk4.z = f2bf(a[2] + bj); pk4.w = f2bf(a[3] + bj);
      *(ushort4*)&qOut[(slab << 14) + (clo << 10) + nb] = pk4;
    }
    // k: QK-row layout
    {
      const float bj = bc[512 + co];
      floatx4 a = ak[mi];
      ushort4 pk4;
      pk4.x = f2bf(a[0] + bj); pk4.y = f2bf(a[1] + bj);
      pk4.z = f2bf(a[2] + bj); pk4.w = f2bf(a[3] + bj);
      *(ushort4*)&kOut[(slab << 14) + (clo << 10) + nb] = pk4;
    }
    // v: V^T scatter
    {
      const float bj = bc[256 + co];
      floatx4 a = av[mi];
      const int base = (slab << 14) + (clo << 6);
#pragma unroll
      for (int i = 0; i < 4; ++i) {
        const int n = nb + i;
        vOut[base + ((n & 15) << 10) + (n >> 4)] = f2bf(a[i] + bj);
      }
    }
  }
}

// ---------------------------------------------------------------------------
// MFMA attention per (b,h) slab: softmax(Q K^T * 0.25) V.  [R5-verified]
//   qg, kg : bf16 [slab][1024 m][16 d];  vg : bf16 [slab][16 d][1024 m]
//   out2   : bf16 [8][1024 m][256], c = h*16+d
// ---------------------------------------------------------------------------
__global__ __launch_bounds__(256) void attn_mfma_kernel(
    const unsigned short* __restrict__ qg,
    const unsigned short* __restrict__ kg,
    const unsigned short* __restrict__ vg,
    unsigned short* __restrict__ out2) {
  __shared__ __align__(16) unsigned short Kc[16384];     // [key][16]
  __shared__ __align__(16) unsigned short Vt[16][1032];  // [d][key], padded
  __shared__ __align__(16) unsigned short Pb[4][32][40]; // per-wave P
  __shared__ float lb[4][32];
  const int t    = threadIdx.x;
  const int w    = t >> 6;
  const int lane = t & 63;
  const int slab = blockIdx.x >> 3;
  const int rb   = blockIdx.x & 7;
  const int b = slab >> 4;
  const int h = slab & 15;
  const int l31  = lane & 31;
  const int hl   = lane >> 5;
  const int l15  = lane & 15;
  const int quad = lane >> 4;

#pragma unroll
  for (int j = 0; j < 8; ++j) {
    const int id = (j << 8) + t;
    const int e  = id << 3;
    *(uint4*)&Kc[e] = *(const uint4*)&kg[(slab << 14) + e];
    const int d = e >> 10, ky = e & 1023;
    *(uint4*)&Vt[d][ky] = *(const uint4*)&vg[(slab << 14) + e];
  }

  const int row0 = (rb << 7) + (w << 5);
  const short8 qa =
      *(const short8*)&qg[(slab << 14) + ((row0 + l31) << 4) + (hl << 3)];

  float lsum[16] = {};
  floatx4 acco[2] = {};
  const float sc = 0.25f * 1.4426950408889634f;

  __syncthreads();

  for (int kc = 0; kc < 1024; kc += 32) {
    const short8 kb = *(const short8*)&Kc[((kc + l31) << 4) + (hl << 3)];
    floatx16 s = {};
    s = __builtin_amdgcn_mfma_f32_32x32x16_bf16(qa, kb, s, 0, 0, 0);
#pragma unroll
    for (int r = 0; r < 16; ++r) {
      const float e = exp2f(s[r] * sc);
      lsum[r] += e;
      const int row = (r & 3) + ((r >> 2) << 3) + (hl << 2);
      Pb[w][row][l31] = f2bf(e);
    }
    const short8 vb = *(const short8*)&Vt[l15][kc + (quad << 3)];
#pragma unroll
    for (int tt = 0; tt < 2; ++tt) {
      const short8 pa = *(const short8*)&Pb[w][(tt << 4) + l15][quad << 3];
      acco[tt] =
          __builtin_amdgcn_mfma_f32_16x16x32_bf16(pa, vb, acco[tt], 0, 0, 0);
    }
  }

#pragma unroll
  for (int r = 0; r < 16; ++r) {
    float lv = lsum[r];
    lv += __shfl_xor(lv, 1, 64);
    lv += __shfl_xor(lv, 2, 64);
    lv += __shfl_xor(lv, 4, 64);
    lv += __shfl_xor(lv, 8, 64);
    lv += __shfl_xor(lv, 16, 64);
    lsum[r] = lv;
  }
  {
    const int rr = l31;
    if (((rr >> 2) & 1) == hl) {
      const int reg = (rr & 3) + ((rr >> 3) << 2);
      lb[w][rr] = 1.0f / lsum[reg];
    }
  }
#pragma unroll
  for (int tt = 0; tt < 2; ++tt) {
#pragma unroll
    for (int r = 0; r < 4; ++r) {
      const int nloc = (tt << 4) + (quad << 2) + r;
      const float val = acco[tt][r] * lb[w][nloc];
      const int n = row0 + nloc;
      out2[(((b << 10) + n) << 8) + (h << 4) + l15] = f2bf(val);
    }
  }
}

// ---------------------------------------------------------------------------
// Final linear, MFMA bf16, with one-chunk-ahead B register prefetch.
// ---------------------------------------------------------------------------
__global__ __launch_bounds__(256) void linear_mfma_kernel(
    const unsigned short* __restrict__ inp,  // bf16 [8192][256]
    const unsigned short* __restrict__ wpF,  // fragment order
    void* __restrict__ out, const int* __restrict__ flag) {
  __shared__ unsigned short As[64 * 40];
  const int isf32 = *flag;
  const int t   = threadIdx.x;
  const int m0  = blockIdx.x << 6;
  const int co0 = blockIdx.y << 6;
  const int wv   = t >> 6;
  const int lane = t & 63;
  const int wm = (wv & 1) << 5;
  const int wn = (wv >> 1) << 5;
  const int l15  = lane & 15;
  const int quad = lane >> 4;
  const int cogb = (co0 >> 4) + (wn >> 4);
  const int rowS = t >> 2;
  const int partS = t & 3;

  floatx4 acc[2][2] = {};

  short8 cb0, cb1;
  {
    const unsigned short* wptr = &wpF[(cogb << 9) + (lane << 3)];
    cb0 = *(const short8*)wptr;
    cb1 = *(const short8*)(wptr + 512);
  }
  for (int c8 = 0; c8 < 8; ++c8) {
    const uint4 v = *(const uint4*)&inp[((m0 + rowS) << 8) + (c8 << 5) +
                                        (partS << 3)];
    short8 nb0 = {}, nb1 = {};
    if (c8 + 1 < 8) {
      const unsigned short* wptr =
          &wpF[((((c8 + 1) << 4) + cogb) << 9) + (lane << 3)];
      nb0 = *(const short8*)wptr;
      nb1 = *(const short8*)(wptr + 512);
    }
    __syncthreads();
    *(uint4*)&As[rowS * 40 + (partS << 3)] = v;
    __syncthreads();
    const unsigned short* xs = &As[(wm + l15) * 40 + (quad << 3)];
    const short8 afr0 = *(const short8*)xs;
    const short8 afr1 = *(const short8*)(xs + 16 * 40);
    acc[0][0] = __builtin_amdgcn_mfma_f32_16x16x32_bf16(afr0, cb0,
                                                        acc[0][0], 0, 0, 0);
    acc[0][1] = __builtin_amdgcn_mfma_f32_16x16x32_bf16(afr0, cb1,
                                                        acc[0][1], 0, 0, 0);
    acc[1][0] = __builtin_amdgcn_mfma_f32_16x16x32_bf16(afr1, cb0,
                                                        acc[1][0], 0, 0, 0);
    acc[1][1] = __builtin_amdgcn_mfma_f32_16x16x32_bf16(afr1, cb1,
                                                        acc[1][1], 0, 0, 0);
    cb0 = nb0; cb1 = nb1;
  }
#pragma unroll
  for (int mi = 0; mi < 2; ++mi) {
#pragma unroll
    for (int ni = 0; ni < 2; ++ni) {
      const int co = co0 + wn + (ni << 4) + l15;
      const int mb = m0 + wm + (mi << 4) + (quad << 2);
      floatx4 a = acc[mi][ni];
      if (!isf32) {
        unsigned short* o16 = (unsigned short*)out;
#pragma unroll
        for (int r = 0; r < 4; ++r) o16[(mb + r) * 256 + co] = f2bf(a[r]);
      } else {
        float* o32 = (float*)out;
#pragma unroll
        for (int r = 0; r < 4; ++r) o32[(mb + r) * 256 + co] = a[r];
      }
    }
  }
}

// ---------------------------------------------------------------------------
extern "C" void kernel_launch(void* const* d_in, const int* in_sizes, int n_in,
                              void* d_out, int out_size, void* d_ws,
                              size_t ws_size, hipStream_t stream) {
  const void* x  = d_in[0];
  const void* w3 = d_in[1];
  const void* b3 = d_in[2];
  const void* w5 = d_in[3];
  const void* b5 = d_in[4];
  const void* w7 = d_in[5];
  const void* b7 = d_in[6];
  const void* wp = d_in[7];

  char* p = (char*)d_ws;
  int* flag = (int*)p;                       p += 256;
  unsigned short* xbf = (unsigned short*)p;  p += 4u * 1024 * 1024;
  unsigned short* wF3 = (unsigned short*)p;  p += 131072;
  unsigned short* wF5 = (unsigned short*)p;  p += 1179648;
  unsigned short* wF7 = (unsigned short*)p;  p += 3276800;
  unsigned short* wpF = (unsigned short*)p;  p += 131072;
  float* bc = (float*)p;                     p += 4096;     // [3][256]
  unsigned short* qc  = (unsigned short*)p;  p += 4194304;  // bf16 QK rows
  unsigned short* kT  = (unsigned short*)p;  p += 4194304;  // bf16 QK rows
  unsigned short* vT  = (unsigned short*)p;  p += 4194304;  // bf16 V^T
  unsigned short* o2b = (unsigned short*)p;  p += 4194304;  // bf16 [8192][256]

  detect_kernel<<<1, 256, 0, stream>>>((const unsigned short*)x, flag);

  prep_kernel<<<11265, 256, 0, stream>>>(x, w3, b3, w5, b5, w7, b7, wp, xbf,
                                         wF3, wF5, wF7, wpF, bc, flag);

  convqkv_kernel<<<1024, 256, 0, stream>>>(xbf, wF3, wF5, wF7, bc, qc, vT, kT);

  attn_mfma_kernel<<<1024, 256, 0, stream>>>(qc, kT, vT, o2b);

  dim3 lg(128, 4);
  linear_mfma_kernel<<<lg, 256, 0, stream>>>(o2b, wpF, d_out, flag);
}